// Round 6
// baseline (1013.963 us; speedup 1.0000x reference)
//
#include <hip/hip_runtime.h>

#define DEVFN __device__ __forceinline__

typedef __bf16 bf16x8 __attribute__((ext_vector_type(8)));
typedef float floatx4 __attribute__((ext_vector_type(4)));
typedef unsigned short us4 __attribute__((ext_vector_type(4)));

// ---------- helpers ----------

DEVFN unsigned short f2bf(float x) {
    union { float f; unsigned u; } v; v.f = x;
    v.u += 0x7FFFu + ((v.u >> 16) & 1u);   // RNE
    return (unsigned short)(v.u >> 16);
}

DEVFN float bf2f(unsigned short s) {
    union { unsigned u; float f; } v; v.u = ((unsigned)s) << 16; return v.f;
}

DEVFN float sigm(float x) { return 1.f / (1.f + __expf(-x)); }
DEVFN float tanh_fast(float x) { float t = __expf(2.f * x); return 1.f - 2.f / (t + 1.f); }

DEVFN void gload_lds16(const unsigned short* g, unsigned short* l) {
    __builtin_amdgcn_global_load_lds(
        (__attribute__((address_space(1))) unsigned int*)g,
        (__attribute__((address_space(3))) unsigned int*)l, 16, 0, 0);
}

#define CFENCE asm volatile("" ::: "memory")

// ---------- conversion kernels ----------

__global__ __launch_bounds__(256) void transpose_bt(const float* __restrict__ in,
                                                    unsigned short* __restrict__ out) {
    int idx = blockIdx.x * 256 + threadIdx.x;          // one float4 each
    int k4 = (idx & 255) << 2;
    int row = idx >> 8;                                // t*256 + b
    int t = row >> 8, b = row & 255;
    float4 v = *(const float4*)(in + (size_t)(b * 14 + t) * 1024 + k4);
    us4 o = {f2bf(v.x), f2bf(v.y), f2bf(v.z), f2bf(v.w)};
    *(us4*)(out + (size_t)row * 1024 + k4) = o;
}

__global__ __launch_bounds__(256) void conv_w4(const float* __restrict__ s0, const float* __restrict__ s1,
                                               const float* __restrict__ s2, const float* __restrict__ s3,
                                               unsigned short* __restrict__ d0, unsigned short* __restrict__ d1,
                                               unsigned short* __restrict__ d2, unsigned short* __restrict__ d3) {
    int t = blockIdx.x * 256 + threadIdx.x;
    int which = t >> 20;
    int off = (t & 1048575) << 2;
    const float* s = (which == 0) ? s0 : (which == 1) ? s1 : (which == 2) ? s2 : s3;
    unsigned short* d = (which == 0) ? d0 : (which == 1) ? d1 : (which == 2) ? d2 : d3;
    float4 v = *(const float4*)(s + off);
    us4 o = {f2bf(v.x), f2bf(v.y), f2bf(v.z), f2bf(v.w)};
    *(us4*)(d + off) = o;
}

__global__ __launch_bounds__(256) void conv_cls(const float* __restrict__ in,
                                                unsigned short* __restrict__ out) {
    int t = blockIdx.x * 256 + threadIdx.x;
    int off = t << 2;
    us4 o = {0, 0, 0, 0};
    if (off < 2573312) {
        float4 v = *(const float4*)(in + off);
        o = (us4){f2bf(v.x), f2bf(v.y), f2bf(v.z), f2bf(v.w)};
    }
    *(us4*)(out + off) = o;
}

__global__ __launch_bounds__(256) void bias_interleave(const float* __restrict__ a,
                                                       const float* __restrict__ b,
                                                       float* __restrict__ o4, int n) {
    int i = blockIdx.x * 256 + threadIdx.x;
    if (i < n) {
        int g = i >> 10, h = i & 1023;
        o4[h * 4 + g] = a[i] + b[i];
    }
}

// roll t=0: gates = Xroll only, c_prev = 0, h_prev = 0
__global__ __launch_bounds__(256) void cell_only(const float* __restrict__ pre4,
                                                 float* __restrict__ c_out,
                                                 unsigned short* __restrict__ h_out) {
    int idx = blockIdx.x * 256 + threadIdx.x;
    float4 g = ((const float4*)pre4)[idx];
    float iv = sigm(g.x), fv = sigm(g.y);
    float gv = tanh_fast(g.z), ov = sigm(g.w);
    float cn = iv * gv;
    float hn = ov * tanh_fast(cn);
    c_out[idx] = cn;
    h_out[idx] = f2bf(hn);
}

// ===================================================================
// 8-wave 256x256 fused GEMM (M >= 3072 paths). K=1024, BK=64,
// 2-K-tile LDS ring (128 KB). T4 counted pipeline: tile boundary does
// {barrier; stage(u+2); vmcnt(8); barrier} -- tile u+1's loads get ~2
// compute phases to land; never drains to 0 in steady state.
// ===================================================================
template <int MODE, int PREBF>
__global__ __launch_bounds__(512, 2)
void lstm_fused8(const unsigned short* __restrict__ A1, const unsigned short* __restrict__ W1,
                 const void* __restrict__ pre4,
                 const float* __restrict__ bias4,
                 const float* __restrict__ c_in,
                 float* __restrict__ c_out,
                 unsigned short* __restrict__ h_out,
                 unsigned short* __restrict__ h_alt, int retire_t,
                 float* __restrict__ gout_f,
                 unsigned short* __restrict__ gout_bf,
                 const float* __restrict__ clsb,
                 float* __restrict__ outp, int gx) {
    __shared__ __align__(16) unsigned short lds[2][32768];   // [buf][A(16384)|B(16384)]

    const int tid = threadIdx.x;
    const int nwg = gridDim.x;
    int id = blockIdx.x;
    {   // bijective XCD swizzle (m204)
        int q = nwg >> 3, r = nwg & 7;
        int xcd = id & 7, pos = id >> 3;
        id = (xcd < r ? xcd * (q + 1) : r * (q + 1) + (xcd - r) * q) + pos;
    }
    const int bx = id % gx;
    const int by = id / gx;
    const int m0 = by << 8;
    const int n0h = bx * 64;
    const int n0c = bx * 256;
    const int lane = tid & 63;
    const int wv = tid >> 6;
    const int wm = wv >> 2, wn = wv & 3;       // 2M x 4N waves
    const int r16 = lane & 15;
    const int kg = lane >> 4;

    auto stage = [&](int u, int buf) {
        const int ko = u * 64;
#pragma unroll
        for (int is = 0; is < 4; ++is) {
            int c = is * 512 + tid;
            int row = c >> 3, kq = c & 7, kqg = kq ^ (row & 7);
            gload_lds16(A1 + (size_t)(m0 + row) * 1024 + ko + kqg * 8, &lds[buf][c * 8]);
        }
#pragma unroll
        for (int is = 0; is < 4; ++is) {
            int c = is * 512 + tid;
            int row = c >> 3, kq = c & 7, kqg = kq ^ (row & 7);
            int wr;
            if (MODE == 2) wr = n0c + row;
            else wr = ((row >> 4) & 3) * 1024 + n0h + ((row >> 6) << 4) + (row & 15);
            gload_lds16(W1 + (size_t)wr * 1024 + ko + kqg * 8, &lds[buf][16384 + c * 8]);
        }
    };

    floatx4 acc[8][4];
#pragma unroll
    for (int i = 0; i < 8; ++i)
#pragma unroll
        for (int j = 0; j < 4; ++j) acc[i][j] = {0.f, 0.f, 0.f, 0.f};

    stage(0, 0);
    stage(1, 1);
    asm volatile("s_waitcnt vmcnt(8)" ::: "memory");   // tile0 ready, tile1 in flight
    __builtin_amdgcn_s_barrier();
    CFENCE;

#pragma unroll 2
    for (int u = 0; u < 16; ++u) {
        const int cur = u & 1;
        const unsigned short* la = &lds[cur][0];
        const unsigned short* lb = &lds[cur][16384];

        bf16x8 b[4][2];
#pragma unroll
        for (int j = 0; j < 4; ++j)
#pragma unroll
            for (int kk = 0; kk < 2; ++kk) {
                int row = wn * 64 + j * 16 + r16;
                b[j][kk] = *(const bf16x8*)&lb[row * 64 + (((kk << 2) + kg) ^ (row & 7)) * 8];
            }
#pragma unroll
        for (int qp = 0; qp < 4; ++qp) {
            bf16x8 a[2][2];
#pragma unroll
            for (int ii = 0; ii < 2; ++ii)
#pragma unroll
                for (int kk = 0; kk < 2; ++kk) {
                    int row = wm * 128 + (qp * 2 + ii) * 16 + r16;
                    a[ii][kk] = *(const bf16x8*)&la[row * 64 + (((kk << 2) + kg) ^ (row & 7)) * 8];
                }
            __builtin_amdgcn_s_setprio(1);
#pragma unroll
            for (int ii = 0; ii < 2; ++ii)
#pragma unroll
                for (int j = 0; j < 4; ++j)
#pragma unroll
                    for (int kk = 0; kk < 2; ++kk)
                        acc[qp * 2 + ii][j] = __builtin_amdgcn_mfma_f32_16x16x32_bf16(
                            a[ii][kk], b[j][kk], acc[qp * 2 + ii][j], 0, 0, 0);
            __builtin_amdgcn_s_setprio(0);
            if (qp < 3) __builtin_amdgcn_s_barrier();
        }
        if (u < 15) {
            __builtin_amdgcn_s_barrier();          // all waves done reading lds[cur]
            if (u < 14) {
                stage(u + 2, cur);
                asm volatile("s_waitcnt vmcnt(8)" ::: "memory");   // tile u+1 ready
            } else {
                asm volatile("s_waitcnt vmcnt(0)" ::: "memory");   // tile 15 ready
            }
            __builtin_amdgcn_s_barrier();
            CFENCE;
        }
    }

    // ---------- epilogue ----------
    if (MODE == 2) {
#pragma unroll
        for (int i = 0; i < 8; ++i)
#pragma unroll
            for (int j = 0; j < 4; ++j)
#pragma unroll
                for (int rg = 0; rg < 4; ++rg) {
                    int m = m0 + wm * 128 + i * 16 + kg * 4 + rg;
                    int gn = n0c + wn * 64 + j * 16 + r16;
                    if (gn < 2513) {
                        int bb = m & 255, tt = m >> 8;
                        outp[(size_t)(bb * 14 + tt) * 2513 + gn] = acc[i][j][rg] + clsb[gn];
                    }
                }
        return;
    }

    const int h = n0h + wn * 16 + r16;
    float4 bv = make_float4(0.f, 0.f, 0.f, 0.f);
    if (bias4) bv = *(const float4*)(bias4 + (size_t)h * 4);
    unsigned short* hw = h_out;
    if (MODE == 1 && by == retire_t) hw = h_alt;   // 256-row tile == one branch

#pragma unroll
    for (int i = 0; i < 8; ++i)
#pragma unroll
        for (int rg = 0; rg < 4; ++rg) {
            int m = m0 + wm * 128 + i * 16 + kg * 4 + rg;
            size_t mh = (size_t)m * 1024 + h;
            float gi_ = acc[i][0][rg] + bv.x;
            float gf_ = acc[i][1][rg] + bv.y;
            float gg_ = acc[i][2][rg] + bv.z;
            float go_ = acc[i][3][rg] + bv.w;
            if (MODE == 0) {
                *(float4*)(gout_f + mh * 4) = make_float4(gi_, gf_, gg_, go_);
            } else if (MODE == 3) {
                us4 o = {f2bf(gi_), f2bf(gf_), f2bf(gg_), f2bf(go_)};
                *(us4*)(gout_bf + mh * 4) = o;
            } else {
                if (pre4) {
                    if (PREBF) {
                        us4 pv = *(const us4*)((const unsigned short*)pre4 + mh * 4);
                        gi_ += bf2f(pv.x); gf_ += bf2f(pv.y);
                        gg_ += bf2f(pv.z); go_ += bf2f(pv.w);
                    } else {
                        float4 pv = ((const float4*)pre4)[mh];
                        gi_ += pv.x; gf_ += pv.y; gg_ += pv.z; go_ += pv.w;
                    }
                }
                float co = c_in ? c_in[mh] : 0.f;
                float iv = sigm(gi_), fv = sigm(gf_);
                float gv = tanh_fast(gg_), ov = sigm(go_);
                float cn = fv * co + iv * gv;
                float hn = ov * tanh_fast(cn);
                c_out[mh] = cn;
                hw[mh] = f2bf(hn);
            }
        }
}

// ===================================================================
// 4-wave fused LSTM-cell GEMM (roll chain + mid/small unroll steps).
// Ring-4 LDS, 3 tiles prefetched ahead, counted waits (10/5/0) --
// ~3 phases of latency window for the serial roll chain.
// ===================================================================
template <int BM, int PREBF>
__global__ __launch_bounds__(256)
void lstm_small(const unsigned short* __restrict__ A1, const unsigned short* __restrict__ W1,
                const void* __restrict__ pre4,
                const float* __restrict__ c_in,
                float* __restrict__ c_out,
                unsigned short* __restrict__ h_out,
                unsigned short* __restrict__ h_alt, int retire_t,
                int gx) {
    constexpr int FM = BM / 32;
    constexpr int AISS = (BM * 64 * 2) / 4096;   // 1 (BM=32) or 2 (BM=64)
    constexpr int LOADS = AISS + 4;              // per-thread loads per tile
    constexpr int ATILE = BM * 64;

    __shared__ __align__(16) unsigned short lds[4][ATILE + 8192];

    const int tid = threadIdx.x;
    const int nwg = gridDim.x;
    int id = blockIdx.x;
    id = ((id & 7) * (nwg >> 3)) + (id >> 3);   // chunked swizzle (nwg % 8 == 0)
    const int bx = id % gx;
    const int by = id / gx;
    const int m0 = by * BM;
    const int n0 = bx * 32;
    const int lane = tid & 63;
    const int wv = tid >> 6;
    const int wm = wv >> 1, wn = wv & 1;
    const int r16 = lane & 15;
    const int kg = lane >> 4;

    auto stage = [&](int kt, int buf) {
        const int ko = kt * 64;
#pragma unroll
        for (int is = 0; is < AISS; ++is) {
            int c = is * 256 + tid;
            int row = c >> 3, kq = c & 7, kqg = kq ^ (row & 7);
            gload_lds16(A1 + (size_t)(m0 + row) * 1024 + ko + kqg * 8, &lds[buf][c * 8]);
        }
#pragma unroll
        for (int is = 0; is < 4; ++is) {
            int c = is * 256 + tid;
            int row = c >> 3, kq = c & 7, kqg = kq ^ (row & 7);
            int wr = ((row >> 4) & 3) * 1024 + n0 + ((row >> 6) << 4) + (row & 15);
            gload_lds16(W1 + (size_t)wr * 1024 + ko + kqg * 8, &lds[buf][ATILE + c * 8]);
        }
    };

    floatx4 acc[FM][4];
#pragma unroll
    for (int i = 0; i < FM; ++i)
#pragma unroll
        for (int j = 0; j < 4; ++j) acc[i][j] = {0.f, 0.f, 0.f, 0.f};

    stage(0, 0);
    stage(1, 1);
    stage(2, 2);
    asm volatile("s_waitcnt vmcnt(%0)" :: "n"(2 * LOADS) : "memory");  // tile0 ready
    __builtin_amdgcn_s_barrier();
    CFENCE;

#pragma unroll 4
    for (int u = 0; u < 16; ++u) {
        const int cur = u & 3;
#pragma unroll
        for (int kk = 0; kk < 2; ++kk) {
            bf16x8 a[FM], b[4];
            const int kqg = kk * 4 + kg;
#pragma unroll
            for (int i = 0; i < FM; ++i) {
                int row = wm * (BM / 2) + i * 16 + r16;
                a[i] = *(const bf16x8*)&lds[cur][row * 64 + (kqg ^ (row & 7)) * 8];
            }
#pragma unroll
            for (int j = 0; j < 4; ++j) {
                int row = wn * 64 + j * 16 + r16;
                b[j] = *(const bf16x8*)&lds[cur][ATILE + row * 64 + (kqg ^ (row & 7)) * 8];
            }
#pragma unroll
            for (int i = 0; i < FM; ++i)
#pragma unroll
                for (int j = 0; j < 4; ++j)
                    acc[i][j] = __builtin_amdgcn_mfma_f32_16x16x32_bf16(a[i], b[j], acc[i][j], 0, 0, 0);
        }
        if (u < 15) {
            __builtin_amdgcn_s_barrier();          // all waves done reading lds[cur]
            if (u < 13) {
                stage(u + 3, (u + 3) & 3);
                asm volatile("s_waitcnt vmcnt(%0)" :: "n"(2 * LOADS) : "memory");
            } else if (u == 13) {
                asm volatile("s_waitcnt vmcnt(%0)" :: "n"(LOADS) : "memory");
            } else {
                asm volatile("s_waitcnt vmcnt(0)" ::: "memory");
            }
            __builtin_amdgcn_s_barrier();
            CFENCE;
        }
    }

    const int h = n0 + wn * 16 + r16;
    unsigned short* hw = h_out;
    if ((m0 >> 8) == retire_t) hw = h_alt;

#pragma unroll
    for (int i = 0; i < FM; ++i)
#pragma unroll
        for (int rg = 0; rg < 4; ++rg) {
            int m = m0 + wm * (BM / 2) + i * 16 + kg * 4 + rg;
            size_t mh = (size_t)m * 1024 + h;
            float gi_ = acc[i][0][rg];
            float gf_ = acc[i][1][rg];
            float gg_ = acc[i][2][rg];
            float go_ = acc[i][3][rg];
            if (PREBF) {
                us4 pv = *(const us4*)((const unsigned short*)pre4 + mh * 4);
                gi_ += bf2f(pv.x); gf_ += bf2f(pv.y);
                gg_ += bf2f(pv.z); go_ += bf2f(pv.w);
            } else {
                float4 pv = ((const float4*)pre4)[mh];
                gi_ += pv.x; gf_ += pv.y; gg_ += pv.z; go_ += pv.w;
            }
            float co = c_in ? c_in[mh] : 0.f;
            float iv = sigm(gi_), fv = sigm(gf_);
            float gv = tanh_fast(gg_), ov = sigm(go_);
            float cn = fv * co + iv * gv;
            float hn = ov * tanh_fast(cn);
            c_out[mh] = cn;
            hw[mh] = f2bf(hn);
        }
}

// ---------- launch ----------

extern "C" void kernel_launch(void* const* d_in, const int* in_sizes, int n_in,
                              void* d_out, int out_size, void* d_ws, size_t ws_size,
                              hipStream_t stream) {
    (void)in_sizes; (void)n_in; (void)out_size; (void)ws_size;
    const float* inputs   = (const float*)d_in[0];
    const float* roll_Wih = (const float*)d_in[1];
    const float* roll_Whh = (const float*)d_in[2];
    const float* roll_bih = (const float*)d_in[3];
    const float* roll_bhh = (const float*)d_in[4];
    const float* un_Wih   = (const float*)d_in[5];
    const float* un_Whh   = (const float*)d_in[6];
    const float* un_bih   = (const float*)d_in[7];
    const float* un_bhh   = (const float*)d_in[8];
    const float* cls_Wf   = (const float*)d_in[9];
    const float* cls_b    = (const float*)d_in[10];
    float* out = (float*)d_out;

    char* ws = (char*)d_ws;
    size_t off = 0;
    auto alloc = [&](size_t bytes) -> char* {
        char* p = ws + off;
        off += (bytes + 255) & ~(size_t)255;
        return p;
    };
    unsigned short* xt   = (unsigned short*)alloc(3584ull * 1024 * 2);
    unsigned short* rWih = (unsigned short*)alloc(4096ull * 1024 * 2);
    unsigned short* rWhh = (unsigned short*)alloc(4096ull * 1024 * 2);
    unsigned short* uWih = (unsigned short*)alloc(4096ull * 1024 * 2);
    unsigned short* uWhh = (unsigned short*)alloc(4096ull * 1024 * 2);
    unsigned short* cWp  = (unsigned short*)alloc(2560ull * 1024 * 2);
    float* rbias4 = (float*)alloc(1024 * 4 * 4);
    float* ubias4 = (float*)alloc(1024 * 4 * 4);
    unsigned short* XpreB = (unsigned short*)alloc(3584ull * 4096 * 2);
    float* Xroll  = (float*)alloc(3584ull * 4096 * 4);
    float* uc     = (float*)alloc(3584ull * 1024 * 4);
    unsigned short* hb0    = (unsigned short*)alloc(3584ull * 1024 * 2);
    unsigned short* hb1    = (unsigned short*)alloc(3584ull * 1024 * 2);
    unsigned short* hfinal = (unsigned short*)alloc(3584ull * 1024 * 2);

    const size_t SF = 256 * 1024;

    // 1) conversions
    transpose_bt<<<3584, 256, 0, stream>>>(inputs, xt);
    conv_w4<<<16384, 256, 0, stream>>>(roll_Wih, roll_Whh, un_Wih, un_Whh,
                                       rWih, rWhh, uWih, uWhh);
    conv_cls<<<2560, 256, 0, stream>>>(cls_Wf, cWp);
    bias_interleave<<<16, 256, 0, stream>>>(roll_bih, roll_bhh, rbias4, 4096);
    bias_interleave<<<16, 256, 0, stream>>>(un_bih, un_bhh, ubias4, 4096);

    // 2) x-projections (hoisted; 8-wave kernel, M=3584 -> 224 blocks)
    lstm_fused8<3, 0><<<224, 512, 0, stream>>>(
        xt, uWih, nullptr, ubias4, nullptr, nullptr, nullptr, nullptr, -1,
        nullptr, XpreB, nullptr, nullptr, 16);
    lstm_fused8<0, 0><<<224, 512, 0, stream>>>(
        xt, rWih, nullptr, rbias4, nullptr, nullptr, nullptr, nullptr, -1,
        Xroll, nullptr, nullptr, nullptr, 16);

    // 3) rolling LSTM: t=0 elementwise, t>=1 ring-4 small GEMM
    cell_only<<<1024, 256, 0, stream>>>(Xroll, uc, hb0);
    for (int t = 1; t < 14; ++t) {
        lstm_small<32, 0><<<256, 256, 0, stream>>>(
            hb0 + (size_t)(t - 1) * SF, rWhh,
            Xroll + (size_t)t * SF * 4,
            uc + (size_t)(t - 1) * SF, uc + (size_t)t * SF,
            hb0 + (size_t)t * SF, nullptr, -1, 32);
    }

    // 4) unrolling LSTM: shrinking prefix; retiring branch -> hfinal
    for (int s = 0; s <= 14; ++s) {
        int nb = (15 - s < 14) ? (15 - s) : 14;
        int M = nb * 256;
        const unsigned short* hsrc = (s & 1) ? hb1 : hb0;
        unsigned short* hdst = (s & 1) ? hb0 : hb1;
        int rt = (s >= 1) ? (14 - s) : -1;
        if (M >= 3072) {
            lstm_fused8<1, 1><<<16 * (M / 256), 512, 0, stream>>>(
                hsrc, uWhh, XpreB, nullptr, uc, uc, hdst, hfinal, rt,
                nullptr, nullptr, nullptr, nullptr, 16);
        } else if (M >= 512) {
            lstm_small<64, 1><<<32 * (M / 64), 256, 0, stream>>>(
                hsrc, uWhh, XpreB, uc, uc, hdst, hfinal, rt, 32);
        } else {
            lstm_small<32, 1><<<32 * (M / 32), 256, 0, stream>>>(
                hsrc, uWhh, XpreB, uc, uc, hdst, hfinal, rt, 32);
        }
    }

    // 5) classifier from hfinal (grid 14 x 10 = 140, bijective swizzle)
    lstm_fused8<2, 0><<<140, 512, 0, stream>>>(
        hfinal, cWp, nullptr, nullptr, nullptr, nullptr, nullptr, nullptr, -1,
        nullptr, nullptr, cls_b, out, 10);
}

// Round 7
// 821.922 us; speedup vs baseline: 1.2336x; 1.2336x over previous
//
#include <hip/hip_runtime.h>

#define DEVFN __device__ __forceinline__

typedef __bf16 bf16x8 __attribute__((ext_vector_type(8)));
typedef float floatx4 __attribute__((ext_vector_type(4)));
typedef unsigned short us4 __attribute__((ext_vector_type(4)));

// ---------- helpers ----------

DEVFN unsigned short f2bf(float x) {
    union { float f; unsigned u; } v; v.f = x;
    v.u += 0x7FFFu + ((v.u >> 16) & 1u);   // RNE
    return (unsigned short)(v.u >> 16);
}

DEVFN float bf2f(unsigned short s) {
    union { unsigned u; float f; } v; v.u = ((unsigned)s) << 16; return v.f;
}

DEVFN float sigm(float x) { return 1.f / (1.f + __expf(-x)); }
DEVFN float tanh_fast(float x) { float t = __expf(2.f * x); return 1.f - 2.f / (t + 1.f); }

DEVFN void gload_lds16(const unsigned short* g, unsigned short* l) {
    __builtin_amdgcn_global_load_lds(
        (__attribute__((address_space(1))) unsigned int*)g,
        (__attribute__((address_space(3))) unsigned int*)l, 16, 0, 0);
}

#define CFENCE asm volatile("" ::: "memory")

// ---------- conversion kernels ----------

__global__ __launch_bounds__(256) void transpose_bt(const float* __restrict__ in,
                                                    unsigned short* __restrict__ out) {
    int idx = blockIdx.x * 256 + threadIdx.x;          // one float4 each
    int k4 = (idx & 255) << 2;
    int row = idx >> 8;                                // t*256 + b
    int t = row >> 8, b = row & 255;
    float4 v = *(const float4*)(in + (size_t)(b * 14 + t) * 1024 + k4);
    us4 o = {f2bf(v.x), f2bf(v.y), f2bf(v.z), f2bf(v.w)};
    *(us4*)(out + (size_t)row * 1024 + k4) = o;
}

__global__ __launch_bounds__(256) void conv_w4(const float* __restrict__ s0, const float* __restrict__ s1,
                                               const float* __restrict__ s2, const float* __restrict__ s3,
                                               unsigned short* __restrict__ d0, unsigned short* __restrict__ d1,
                                               unsigned short* __restrict__ d2, unsigned short* __restrict__ d3) {
    int t = blockIdx.x * 256 + threadIdx.x;
    int which = t >> 20;
    int off = (t & 1048575) << 2;
    const float* s = (which == 0) ? s0 : (which == 1) ? s1 : (which == 2) ? s2 : s3;
    unsigned short* d = (which == 0) ? d0 : (which == 1) ? d1 : (which == 2) ? d2 : d3;
    float4 v = *(const float4*)(s + off);
    us4 o = {f2bf(v.x), f2bf(v.y), f2bf(v.z), f2bf(v.w)};
    *(us4*)(d + off) = o;
}

__global__ __launch_bounds__(256) void conv_cls(const float* __restrict__ in,
                                                unsigned short* __restrict__ out) {
    int t = blockIdx.x * 256 + threadIdx.x;
    int off = t << 2;
    us4 o = {0, 0, 0, 0};
    if (off < 2573312) {
        float4 v = *(const float4*)(in + off);
        o = (us4){f2bf(v.x), f2bf(v.y), f2bf(v.z), f2bf(v.w)};
    }
    *(us4*)(out + off) = o;
}

__global__ __launch_bounds__(256) void bias_interleave(const float* __restrict__ a,
                                                       const float* __restrict__ b,
                                                       float* __restrict__ o4, int n) {
    int i = blockIdx.x * 256 + threadIdx.x;
    if (i < n) {
        int g = i >> 10, h = i & 1023;
        o4[h * 4 + g] = a[i] + b[i];
    }
}

// roll t=0: gates = XrollB (bf16) only, c_prev = 0, h_prev = 0
__global__ __launch_bounds__(256) void cell_only(const unsigned short* __restrict__ pre4b,
                                                 float* __restrict__ c_out,
                                                 unsigned short* __restrict__ h_out) {
    int idx = blockIdx.x * 256 + threadIdx.x;          // (m,h) over 256*1024
    us4 pv = *(const us4*)(pre4b + (size_t)idx * 4);
    float iv = sigm(bf2f(pv.x)), fv = sigm(bf2f(pv.y));
    float gv = tanh_fast(bf2f(pv.z)), ov = sigm(bf2f(pv.w));
    float cn = iv * gv;
    float hn = ov * tanh_fast(cn);
    c_out[idx] = cn;
    h_out[idx] = f2bf(hn);
}

// ===================================================================
// lstm_big: BM=128, BK=32, ring-2 double-buffer, LDS 32 KB -> 5 blk/CU.
// Issue-early staging, counted boundary vmcnt(4) (never drains to 0
// mid-loop). 4 waves 2Mx2N, per-wave 64x64 output.
// Swizzle: chunk kq ^ ((row>>1)&3) -- per-wave frag read is a bijective
// contiguous 1 KB LDS region (2-way bank alias only = free).
// MODE 1: fused LSTM cell (pre4b bf16 gate-interleaved)
// MODE 3: gate-proj store bf16 (+bias4)
// MODE 2: classifier (+clsb, remap to [b,t,n])
// ===================================================================
template <int MODE>
__global__ __launch_bounds__(256)
void lstm_big(const unsigned short* __restrict__ A1, const unsigned short* __restrict__ W1,
              const unsigned short* __restrict__ pre4b,
              const float* __restrict__ bias4,
              const float* __restrict__ c_in,
              float* __restrict__ c_out,
              unsigned short* __restrict__ h_out,
              unsigned short* __restrict__ h_alt, int retire_t,
              unsigned short* __restrict__ gout_bf,
              const float* __restrict__ clsb,
              float* __restrict__ outp, int gx) {
    __shared__ __align__(16) unsigned short lds[2][8192];   // [buf][A 4096 | B 4096]

    const int tid = threadIdx.x;
    const int nwg = gridDim.x;
    int id = blockIdx.x;
    id = ((id & 7) * (nwg >> 3)) + (id >> 3);   // XCD-chunked swizzle (nwg % 8 == 0)
    const int bx = id % gx;
    const int by = id / gx;
    const int m0 = by * 128;
    const int n0h = bx * 32;                    // MODE 1/3: 32 h per block
    const int n0c = bx * 128;                   // MODE 2
    const int lane = tid & 63;
    const int wv = tid >> 6;
    const int wm = wv >> 1, wn = wv & 1;        // 2M x 2N waves
    const int r16 = lane & 15;
    const int kg = lane >> 4;

    auto stage = [&](int u, int buf) {
        const int ko = u * 32;
#pragma unroll
        for (int is = 0; is < 2; ++is) {
            int c = is * 256 + tid;             // 0..511
            int row = c >> 2, kq = c & 3;
            int kqg = kq ^ ((row >> 1) & 3);    // pre-swizzled source chunk
            gload_lds16(A1 + (size_t)(m0 + row) * 1024 + ko + kqg * 8, &lds[buf][c * 8]);
        }
#pragma unroll
        for (int is = 0; is < 2; ++is) {
            int c = is * 256 + tid;
            int row = c >> 2, kq = c & 3;
            int kqg = kq ^ ((row >> 1) & 3);
            int wr;
            if (MODE == 2) wr = n0c + row;
            else wr = ((row >> 4) & 3) * 1024 + n0h + ((row >> 6) << 4) + (row & 15);
            gload_lds16(W1 + (size_t)wr * 1024 + ko + kqg * 8, &lds[buf][4096 + c * 8]);
        }
    };

    floatx4 acc[4][4];
#pragma unroll
    for (int i = 0; i < 4; ++i)
#pragma unroll
        for (int j = 0; j < 4; ++j) acc[i][j] = {0.f, 0.f, 0.f, 0.f};

    stage(0, 0);
    stage(1, 1);
    asm volatile("s_waitcnt vmcnt(4)" ::: "memory");   // tile0 landed, tile1 in flight
    __builtin_amdgcn_s_barrier();
    CFENCE;

#pragma unroll 2
    for (int u = 0; u < 32; ++u) {
        const int cur = u & 1;
        bf16x8 a[4], b[4];
#pragma unroll
        for (int i = 0; i < 4; ++i) {
            int row = wm * 64 + i * 16 + r16;
            a[i] = *(const bf16x8*)&lds[cur][row * 32 + (kg ^ ((row >> 1) & 3)) * 8];
        }
#pragma unroll
        for (int j = 0; j < 4; ++j) {
            int row = wn * 64 + j * 16 + r16;
            b[j] = *(const bf16x8*)&lds[cur][4096 + row * 32 + (kg ^ ((row >> 1) & 3)) * 8];
        }
        __builtin_amdgcn_s_setprio(1);
#pragma unroll
        for (int i = 0; i < 4; ++i)
#pragma unroll
            for (int j = 0; j < 4; ++j)
                acc[i][j] = __builtin_amdgcn_mfma_f32_16x16x32_bf16(a[i], b[j], acc[i][j], 0, 0, 0);
        __builtin_amdgcn_s_setprio(0);

        if (u < 31) {
            __builtin_amdgcn_s_barrier();          // all waves done reading lds[cur]
            if (u < 30) {
                stage(u + 2, cur);
                asm volatile("s_waitcnt vmcnt(4)" ::: "memory");   // tile u+1 ready
            } else {
                asm volatile("s_waitcnt vmcnt(0)" ::: "memory");   // tile 31 ready
            }
            __builtin_amdgcn_s_barrier();
            CFENCE;
        }
    }

    // ---------- epilogue ----------
    if (MODE == 2) {
#pragma unroll
        for (int i = 0; i < 4; ++i)
#pragma unroll
            for (int j = 0; j < 4; ++j)
#pragma unroll
                for (int rg = 0; rg < 4; ++rg) {
                    int m = m0 + wm * 64 + i * 16 + kg * 4 + rg;
                    int gn = n0c + wn * 64 + j * 16 + r16;
                    if (gn < 2513) {
                        int bb = m & 255, tt = m >> 8;
                        outp[(size_t)(bb * 14 + tt) * 2513 + gn] = acc[i][j][rg] + clsb[gn];
                    }
                }
        return;
    }

    const int h = n0h + wn * 16 + r16;
    float4 bv = make_float4(0.f, 0.f, 0.f, 0.f);
    if (MODE == 3 && bias4) bv = *(const float4*)(bias4 + (size_t)h * 4);
    unsigned short* hw = h_out;
    if (MODE == 1 && (m0 >> 8) == retire_t) hw = h_alt;

#pragma unroll
    for (int i = 0; i < 4; ++i)
#pragma unroll
        for (int rg = 0; rg < 4; ++rg) {
            int m = m0 + wm * 64 + i * 16 + kg * 4 + rg;
            size_t mh = (size_t)m * 1024 + h;
            float gi_ = acc[i][0][rg] + bv.x;
            float gf_ = acc[i][1][rg] + bv.y;
            float gg_ = acc[i][2][rg] + bv.z;
            float go_ = acc[i][3][rg] + bv.w;
            if (MODE == 3) {
                us4 o = {f2bf(gi_), f2bf(gf_), f2bf(gg_), f2bf(go_)};
                *(us4*)(gout_bf + mh * 4) = o;
            } else {
                us4 pv = *(const us4*)(pre4b + mh * 4);
                gi_ += bf2f(pv.x); gf_ += bf2f(pv.y);
                gg_ += bf2f(pv.z); go_ += bf2f(pv.w);
                float co = c_in[mh];
                float iv = sigm(gi_), fv = sigm(gf_);
                float gv = tanh_fast(gg_), ov = sigm(go_);
                float cn = fv * co + iv * gv;
                float hn = ov * tanh_fast(cn);
                c_out[mh] = cn;
                hw[mh] = f2bf(hn);
            }
        }
}

// ===================================================================
// lstm_small: BM=32, BK=64, ring-4 (80 KB -> 2 blk/CU), 3 tiles ahead,
// counted waits. For the serial roll chain and the small unroll tail.
// Always fused-cell with bf16 pre.
// ===================================================================
__global__ __launch_bounds__(256)
void lstm_small(const unsigned short* __restrict__ A1, const unsigned short* __restrict__ W1,
                const unsigned short* __restrict__ pre4b,
                const float* __restrict__ c_in,
                float* __restrict__ c_out,
                unsigned short* __restrict__ h_out,
                unsigned short* __restrict__ h_alt, int retire_t,
                int gx) {
    constexpr int ATILE = 32 * 64;               // 2048 shorts
    constexpr int LOADS = 5;                     // 1 A + 4 B issues/thread/tile

    __shared__ __align__(16) unsigned short lds[4][ATILE + 8192];

    const int tid = threadIdx.x;
    const int nwg = gridDim.x;
    int id = blockIdx.x;
    id = ((id & 7) * (nwg >> 3)) + (id >> 3);   // chunked swizzle (nwg % 8 == 0)
    const int bx = id % gx;
    const int by = id / gx;
    const int m0 = by * 32;
    const int n0 = bx * 32;
    const int lane = tid & 63;
    const int wv = tid >> 6;
    const int wm = wv >> 1, wn = wv & 1;
    const int r16 = lane & 15;
    const int kg = lane >> 4;

    auto stage = [&](int kt, int buf) {
        const int ko = kt * 64;
        {
            int c = tid;                         // 256 chunks = 32 rows x 8 kq
            int row = c >> 3, kq = c & 7, kqg = kq ^ (row & 7);
            gload_lds16(A1 + (size_t)(m0 + row) * 1024 + ko + kqg * 8, &lds[buf][c * 8]);
        }
#pragma unroll
        for (int is = 0; is < 4; ++is) {
            int c = is * 256 + tid;
            int row = c >> 3, kq = c & 7, kqg = kq ^ (row & 7);
            int wr = ((row >> 4) & 3) * 1024 + n0 + ((row >> 6) << 4) + (row & 15);
            gload_lds16(W1 + (size_t)wr * 1024 + ko + kqg * 8, &lds[buf][ATILE + c * 8]);
        }
    };

    floatx4 acc[4];
#pragma unroll
    for (int j = 0; j < 4; ++j) acc[j] = {0.f, 0.f, 0.f, 0.f};

    stage(0, 0);
    stage(1, 1);
    stage(2, 2);
    asm volatile("s_waitcnt vmcnt(%0)" :: "n"(2 * LOADS) : "memory");  // tile0 ready
    __builtin_amdgcn_s_barrier();
    CFENCE;

#pragma unroll 4
    for (int u = 0; u < 16; ++u) {
        const int cur = u & 3;
#pragma unroll
        for (int kk = 0; kk < 2; ++kk) {
            bf16x8 a, b[4];
            const int kqg = kk * 4 + kg;
            {
                int row = wm * 16 + r16;
                a = *(const bf16x8*)&lds[cur][row * 64 + (kqg ^ (row & 7)) * 8];
            }
#pragma unroll
            for (int j = 0; j < 4; ++j) {
                int row = wn * 64 + j * 16 + r16;
                b[j] = *(const bf16x8*)&lds[cur][ATILE + row * 64 + (kqg ^ (row & 7)) * 8];
            }
#pragma unroll
            for (int j = 0; j < 4; ++j)
                acc[j] = __builtin_amdgcn_mfma_f32_16x16x32_bf16(a, b[j], acc[j], 0, 0, 0);
        }
        if (u < 15) {
            __builtin_amdgcn_s_barrier();          // all waves done reading lds[cur]
            if (u < 13) {
                stage(u + 3, (u + 3) & 3);
                asm volatile("s_waitcnt vmcnt(%0)" :: "n"(2 * LOADS) : "memory");
            } else if (u == 13) {
                asm volatile("s_waitcnt vmcnt(%0)" :: "n"(LOADS) : "memory");
            } else {
                asm volatile("s_waitcnt vmcnt(0)" ::: "memory");
            }
            __builtin_amdgcn_s_barrier();
            CFENCE;
        }
    }

    const int h = n0 + wn * 16 + r16;
    unsigned short* hw = h_out;
    if ((m0 >> 8) == retire_t) hw = h_alt;

#pragma unroll
    for (int rg = 0; rg < 4; ++rg) {
        int m = m0 + wm * 16 + kg * 4 + rg;
        size_t mh = (size_t)m * 1024 + h;
        us4 pv = *(const us4*)(pre4b + mh * 4);
        float gi_ = acc[0][rg] + bf2f(pv.x);
        float gf_ = acc[1][rg] + bf2f(pv.y);
        float gg_ = acc[2][rg] + bf2f(pv.z);
        float go_ = acc[3][rg] + bf2f(pv.w);
        float co = c_in[mh];
        float iv = sigm(gi_), fv = sigm(gf_);
        float gv = tanh_fast(gg_), ov = sigm(go_);
        float cn = fv * co + iv * gv;
        float hn = ov * tanh_fast(cn);
        c_out[mh] = cn;
        hw[mh] = f2bf(hn);
    }
}

// ---------- launch ----------

extern "C" void kernel_launch(void* const* d_in, const int* in_sizes, int n_in,
                              void* d_out, int out_size, void* d_ws, size_t ws_size,
                              hipStream_t stream) {
    (void)in_sizes; (void)n_in; (void)out_size; (void)ws_size;
    const float* inputs   = (const float*)d_in[0];
    const float* roll_Wih = (const float*)d_in[1];
    const float* roll_Whh = (const float*)d_in[2];
    const float* roll_bih = (const float*)d_in[3];
    const float* roll_bhh = (const float*)d_in[4];
    const float* un_Wih   = (const float*)d_in[5];
    const float* un_Whh   = (const float*)d_in[6];
    const float* un_bih   = (const float*)d_in[7];
    const float* un_bhh   = (const float*)d_in[8];
    const float* cls_Wf   = (const float*)d_in[9];
    const float* cls_b    = (const float*)d_in[10];
    float* out = (float*)d_out;

    char* ws = (char*)d_ws;
    size_t off = 0;
    auto alloc = [&](size_t bytes) -> char* {
        char* p = ws + off;
        off += (bytes + 255) & ~(size_t)255;
        return p;
    };
    unsigned short* xt   = (unsigned short*)alloc(3584ull * 1024 * 2);
    unsigned short* rWih = (unsigned short*)alloc(4096ull * 1024 * 2);
    unsigned short* rWhh = (unsigned short*)alloc(4096ull * 1024 * 2);
    unsigned short* uWih = (unsigned short*)alloc(4096ull * 1024 * 2);
    unsigned short* uWhh = (unsigned short*)alloc(4096ull * 1024 * 2);
    unsigned short* cWp  = (unsigned short*)alloc(2560ull * 1024 * 2);
    float* rbias4 = (float*)alloc(1024 * 4 * 4);
    float* ubias4 = (float*)alloc(1024 * 4 * 4);
    unsigned short* XpreB  = (unsigned short*)alloc(3584ull * 4096 * 2);  // unroll x-proj bf16 [m][h][4]
    unsigned short* XrollB = (unsigned short*)alloc(3584ull * 4096 * 2);  // roll x-proj bf16 [m][h][4]
    float* uc     = (float*)alloc(3584ull * 1024 * 4);
    unsigned short* hb0    = (unsigned short*)alloc(3584ull * 1024 * 2);
    unsigned short* hb1    = (unsigned short*)alloc(3584ull * 1024 * 2);
    unsigned short* hfinal = (unsigned short*)alloc(3584ull * 1024 * 2);

    const size_t SF = 256 * 1024;

    // 1) conversions
    transpose_bt<<<3584, 256, 0, stream>>>(inputs, xt);
    conv_w4<<<16384, 256, 0, stream>>>(roll_Wih, roll_Whh, un_Wih, un_Whh,
                                       rWih, rWhh, uWih, uWhh);
    conv_cls<<<2560, 256, 0, stream>>>(cls_Wf, cWp);
    bias_interleave<<<16, 256, 0, stream>>>(roll_bih, roll_bhh, rbias4, 4096);
    bias_interleave<<<16, 256, 0, stream>>>(un_bih, un_bhh, ubias4, 4096);

    // 2) x-projections (hoisted; grid 28 x 32 = 896)
    lstm_big<3><<<896, 256, 0, stream>>>(
        xt, uWih, nullptr, ubias4, nullptr, nullptr, nullptr, nullptr, -1,
        XpreB, nullptr, nullptr, 32);
    lstm_big<3><<<896, 256, 0, stream>>>(
        xt, rWih, nullptr, rbias4, nullptr, nullptr, nullptr, nullptr, -1,
        XrollB, nullptr, nullptr, 32);

    // 3) rolling LSTM: t=0 elementwise, t>=1 ring-4 small GEMM
    cell_only<<<1024, 256, 0, stream>>>(XrollB, uc, hb0);
    for (int t = 1; t < 14; ++t) {
        lstm_small<<<256, 256, 0, stream>>>(
            hb0 + (size_t)(t - 1) * SF, rWhh,
            XrollB + (size_t)t * SF * 4,
            uc + (size_t)(t - 1) * SF, uc + (size_t)t * SF,
            hb0 + (size_t)t * SF, nullptr, -1, 32);
    }

    // 4) unrolling LSTM: shrinking prefix; retiring branch -> hfinal
    for (int s = 0; s <= 14; ++s) {
        int nb = (15 - s < 14) ? (15 - s) : 14;
        int M = nb * 256;
        const unsigned short* hsrc = (s & 1) ? hb1 : hb0;
        unsigned short* hdst = (s & 1) ? hb0 : hb1;
        int rt = (s >= 1) ? (14 - s) : -1;
        if (M >= 1024) {
            lstm_big<1><<<32 * (M / 128), 256, 0, stream>>>(
                hsrc, uWhh, XpreB, nullptr, uc, uc, hdst, hfinal, rt,
                nullptr, nullptr, nullptr, 32);
        } else {
            lstm_small<<<32 * (M / 32), 256, 0, stream>>>(
                hsrc, uWhh, XpreB, uc, uc, hdst, hfinal, rt, 32);
        }
    }

    // 5) classifier from hfinal (grid 28 x 20 = 560)
    lstm_big<2><<<560, 256, 0, stream>>>(
        hfinal, cWp, nullptr, nullptr, nullptr, nullptr, nullptr, nullptr, -1,
        nullptr, cls_b, out, 20);
}

// Round 8
// 782.934 us; speedup vs baseline: 1.2951x; 1.0498x over previous
//
#include <hip/hip_runtime.h>

#define DEVFN __device__ __forceinline__

typedef __bf16 bf16x8 __attribute__((ext_vector_type(8)));
typedef float floatx4 __attribute__((ext_vector_type(4)));
typedef unsigned short us4 __attribute__((ext_vector_type(4)));

// ---------- helpers ----------

DEVFN unsigned short f2bf(float x) {
    union { float f; unsigned u; } v; v.f = x;
    v.u += 0x7FFFu + ((v.u >> 16) & 1u);   // RNE
    return (unsigned short)(v.u >> 16);
}

DEVFN float bf2f(unsigned short s) {
    union { unsigned u; float f; } v; v.u = ((unsigned)s) << 16; return v.f;
}

DEVFN float sigm(float x) { return 1.f / (1.f + __expf(-x)); }
DEVFN float tanh_fast(float x) { float t = __expf(2.f * x); return 1.f - 2.f / (t + 1.f); }

DEVFN void gload_lds16(const unsigned short* g, unsigned short* l) {
    __builtin_amdgcn_global_load_lds(
        (__attribute__((address_space(1))) unsigned int*)g,
        (__attribute__((address_space(3))) unsigned int*)l, 16, 0, 0);
}

#define CFENCE asm volatile("" ::: "memory")

// ---------- conversion kernels ----------

__global__ __launch_bounds__(256) void transpose_bt(const float* __restrict__ in,
                                                    unsigned short* __restrict__ out) {
    int idx = blockIdx.x * 256 + threadIdx.x;          // one float4 each
    int k4 = (idx & 255) << 2;
    int row = idx >> 8;                                // t*256 + b
    int t = row >> 8, b = row & 255;
    float4 v = *(const float4*)(in + (size_t)(b * 14 + t) * 1024 + k4);
    us4 o = {f2bf(v.x), f2bf(v.y), f2bf(v.z), f2bf(v.w)};
    *(us4*)(out + (size_t)row * 1024 + k4) = o;
}

__global__ __launch_bounds__(256) void conv_w4(const float* __restrict__ s0, const float* __restrict__ s1,
                                               const float* __restrict__ s2, const float* __restrict__ s3,
                                               unsigned short* __restrict__ d0, unsigned short* __restrict__ d1,
                                               unsigned short* __restrict__ d2, unsigned short* __restrict__ d3) {
    int t = blockIdx.x * 256 + threadIdx.x;
    int which = t >> 20;
    int off = (t & 1048575) << 2;
    const float* s = (which == 0) ? s0 : (which == 1) ? s1 : (which == 2) ? s2 : s3;
    unsigned short* d = (which == 0) ? d0 : (which == 1) ? d1 : (which == 2) ? d2 : d3;
    float4 v = *(const float4*)(s + off);
    us4 o = {f2bf(v.x), f2bf(v.y), f2bf(v.z), f2bf(v.w)};
    *(us4*)(d + off) = o;
}

__global__ __launch_bounds__(256) void conv_cls(const float* __restrict__ in,
                                                unsigned short* __restrict__ out) {
    int t = blockIdx.x * 256 + threadIdx.x;
    int off = t << 2;
    us4 o = {0, 0, 0, 0};
    if (off < 2573312) {
        float4 v = *(const float4*)(in + off);
        o = (us4){f2bf(v.x), f2bf(v.y), f2bf(v.z), f2bf(v.w)};
    }
    *(us4*)(out + off) = o;
}

__global__ __launch_bounds__(256) void bias_interleave(const float* __restrict__ a,
                                                       const float* __restrict__ b,
                                                       float* __restrict__ o4, int n) {
    int i = blockIdx.x * 256 + threadIdx.x;
    if (i < n) {
        int g = i >> 10, h = i & 1023;
        o4[h * 4 + g] = a[i] + b[i];
    }
}

// roll t=0: gates = XrollB (bf16) only, c_prev = 0, h_prev = 0
__global__ __launch_bounds__(256) void cell_only(const unsigned short* __restrict__ pre4b,
                                                 float* __restrict__ c_out,
                                                 unsigned short* __restrict__ h_out) {
    int idx = blockIdx.x * 256 + threadIdx.x;
    us4 pv = *(const us4*)(pre4b + (size_t)idx * 4);
    float iv = sigm(bf2f(pv.x)), fv = sigm(bf2f(pv.y));
    float gv = tanh_fast(bf2f(pv.z)), ov = sigm(bf2f(pv.w));
    float cn = iv * gv;
    float hn = ov * tanh_fast(cn);
    c_out[idx] = cn;
    h_out[idx] = f2bf(hn);
}

// ===================================================================
// lstm_big: BM=128, BK=32, ring-2, NH h-columns per block (B-tile =
// 4*NH gate-gathered W rows). NH=64: 48 KB LDS, 32 MFMA vs 12 ds_read
// per wave-tile; NH=32: r7's proven 32 KB config. Counted boundary
// vmcnt(LOADS) never drains to 0 mid-loop.
// MODE 1: fused LSTM cell (pre4b bf16 gate-interleaved)
// MODE 3: gate-proj store bf16 (+bias4)
// MODE 2: classifier, plain 4*NH B-rows (+clsb, remap to [b,t,n])
// ===================================================================
template <int MODE, int NH>
__global__ __launch_bounds__(256, 2)
void lstm_big(const unsigned short* __restrict__ A1, const unsigned short* __restrict__ W1,
              const unsigned short* __restrict__ pre4b,
              const float* __restrict__ bias4,
              const float* __restrict__ c_in,
              float* __restrict__ c_out,
              unsigned short* __restrict__ h_out,
              unsigned short* __restrict__ h_alt, int retire_t,
              unsigned short* __restrict__ gout_bf,
              const float* __restrict__ clsb,
              float* __restrict__ outp, int gx) {
    constexpr int BROWS = 4 * NH;          // B-tile rows
    constexpr int FN = BROWS / 32;         // b-frags per wave (4 or 8)
    constexpr int BISS = BROWS / 64;       // B staging issues (2 or 4)
    constexpr int LOADS = 2 + BISS;        // per-thread loads per tile
    constexpr int ASH = 4096;              // A shorts per buf (128*32)
    constexpr int BSH = BROWS * 32;        // B shorts per buf
    constexpr int HH = NH / 32;            // h-groups per wave (1 or 2)

    __shared__ __align__(16) unsigned short lds[2][ASH + BSH];

    const int tid = threadIdx.x;
    const int nwg = gridDim.x;
    int id = blockIdx.x;
    id = ((id & 7) * (nwg >> 3)) + (id >> 3);   // XCD-chunked swizzle (nwg % 8 == 0)
    const int bx = id % gx;
    const int by = id / gx;
    const int m0 = by * 128;
    const int n0h = bx * NH;                    // MODE 1/3
    const int n0c = bx * BROWS;                 // MODE 2
    const int lane = tid & 63;
    const int wv = tid >> 6;
    const int wm = wv >> 1, wn = wv & 1;        // 2M x 2N waves
    const int r16 = lane & 15;
    const int kg = lane >> 4;

    auto stage = [&](int u, int buf) {
        const int ko = u * 32;
#pragma unroll
        for (int is = 0; is < 2; ++is) {
            int c = is * 256 + tid;
            int row = c >> 2, kq = c & 3;
            int kqg = kq ^ ((row >> 1) & 3);    // pre-swizzled source chunk
            gload_lds16(A1 + (size_t)(m0 + row) * 1024 + ko + kqg * 8, &lds[buf][c * 8]);
        }
#pragma unroll
        for (int is = 0; is < BISS; ++is) {
            int c = is * 256 + tid;
            int row = c >> 2, kq = c & 3;
            int kqg = kq ^ ((row >> 1) & 3);
            int wr;
            if (MODE == 2) wr = n0c + row;
            else wr = ((row >> 4) & 3) * 1024 + n0h + ((row >> 6) << 4) + (row & 15);
            gload_lds16(W1 + (size_t)wr * 1024 + ko + kqg * 8, &lds[buf][ASH + c * 8]);
        }
    };

    floatx4 acc[4][FN];
#pragma unroll
    for (int i = 0; i < 4; ++i)
#pragma unroll
        for (int j = 0; j < FN; ++j) acc[i][j] = {0.f, 0.f, 0.f, 0.f};

    stage(0, 0);
    stage(1, 1);
    asm volatile("s_waitcnt vmcnt(%0)" :: "n"(LOADS) : "memory");  // tile0 ready
    __builtin_amdgcn_s_barrier();
    CFENCE;

#pragma unroll 2
    for (int u = 0; u < 32; ++u) {
        const int cur = u & 1;
        bf16x8 a[4], b[FN];
#pragma unroll
        for (int i = 0; i < 4; ++i) {
            int row = wm * 64 + i * 16 + r16;
            a[i] = *(const bf16x8*)&lds[cur][row * 32 + (kg ^ ((row >> 1) & 3)) * 8];
        }
#pragma unroll
        for (int j = 0; j < FN; ++j) {
            int row = wn * (BROWS / 2) + j * 16 + r16;
            b[j] = *(const bf16x8*)&lds[cur][ASH + row * 32 + (kg ^ ((row >> 1) & 3)) * 8];
        }
        __builtin_amdgcn_s_setprio(1);
#pragma unroll
        for (int i = 0; i < 4; ++i)
#pragma unroll
            for (int j = 0; j < FN; ++j)
                acc[i][j] = __builtin_amdgcn_mfma_f32_16x16x32_bf16(a[i], b[j], acc[i][j], 0, 0, 0);
        __builtin_amdgcn_s_setprio(0);

        if (u < 31) {
            __builtin_amdgcn_s_barrier();          // all waves done reading lds[cur]
            if (u < 30) {
                stage(u + 2, cur);
                asm volatile("s_waitcnt vmcnt(%0)" :: "n"(LOADS) : "memory");
            } else {
                asm volatile("s_waitcnt vmcnt(0)" ::: "memory");
            }
            __builtin_amdgcn_s_barrier();
            CFENCE;
        }
    }

    // ---------- epilogue ----------
    if (MODE == 2) {
#pragma unroll
        for (int i = 0; i < 4; ++i)
#pragma unroll
            for (int j = 0; j < FN; ++j)
#pragma unroll
                for (int rg = 0; rg < 4; ++rg) {
                    int m = m0 + wm * 64 + i * 16 + kg * 4 + rg;
                    int gn = n0c + wn * (BROWS / 2) + j * 16 + r16;
                    if (gn < 2513) {
                        int bb = m & 255, tt = m >> 8;
                        outp[(size_t)(bb * 14 + tt) * 2513 + gn] = acc[i][j][rg] + clsb[gn];
                    }
                }
        return;
    }

    unsigned short* hw = h_out;
    if (MODE == 1 && (m0 >> 8) == retire_t) hw = h_alt;

#pragma unroll
    for (int hh = 0; hh < HH; ++hh) {
        const int h = n0h + wn * (NH / 2) + hh * 16 + r16;
        float4 bv = make_float4(0.f, 0.f, 0.f, 0.f);
        if (MODE == 3 && bias4) bv = *(const float4*)(bias4 + (size_t)h * 4);
#pragma unroll
        for (int i = 0; i < 4; ++i)
#pragma unroll
            for (int rg = 0; rg < 4; ++rg) {
                int m = m0 + wm * 64 + i * 16 + kg * 4 + rg;
                size_t mh = (size_t)m * 1024 + h;
                float gi_ = acc[i][hh * 4 + 0][rg] + bv.x;
                float gf_ = acc[i][hh * 4 + 1][rg] + bv.y;
                float gg_ = acc[i][hh * 4 + 2][rg] + bv.z;
                float go_ = acc[i][hh * 4 + 3][rg] + bv.w;
                if (MODE == 3) {
                    us4 o = {f2bf(gi_), f2bf(gf_), f2bf(gg_), f2bf(go_)};
                    *(us4*)(gout_bf + mh * 4) = o;
                } else {
                    us4 pv = *(const us4*)(pre4b + mh * 4);
                    gi_ += bf2f(pv.x); gf_ += bf2f(pv.y);
                    gg_ += bf2f(pv.z); go_ += bf2f(pv.w);
                    float co = c_in[mh];
                    float iv = sigm(gi_), fv = sigm(gf_);
                    float gv = tanh_fast(gg_), ov = sigm(go_);
                    float cn = fv * co + iv * gv;
                    float hn = ov * tanh_fast(cn);
                    c_out[mh] = cn;
                    hw[mh] = f2bf(hn);
                }
            }
    }
}

// ===================================================================
// lstm_small: BM=32, BK=64, ring-4 (80 KB -> 2 blk/CU), 3 tiles ahead,
// counted waits. For the serial roll chain and the small unroll tail.
// ===================================================================
__global__ __launch_bounds__(256)
void lstm_small(const unsigned short* __restrict__ A1, const unsigned short* __restrict__ W1,
                const unsigned short* __restrict__ pre4b,
                const float* __restrict__ c_in,
                float* __restrict__ c_out,
                unsigned short* __restrict__ h_out,
                unsigned short* __restrict__ h_alt, int retire_t,
                int gx) {
    constexpr int ATILE = 32 * 64;               // 2048 shorts
    constexpr int LOADS = 5;                     // 1 A + 4 B issues/thread/tile

    __shared__ __align__(16) unsigned short lds[4][ATILE + 8192];

    const int tid = threadIdx.x;
    const int nwg = gridDim.x;
    int id = blockIdx.x;
    id = ((id & 7) * (nwg >> 3)) + (id >> 3);   // chunked swizzle (nwg % 8 == 0)
    const int bx = id % gx;
    const int by = id / gx;
    const int m0 = by * 32;
    const int n0 = bx * 32;
    const int lane = tid & 63;
    const int wv = tid >> 6;
    const int wm = wv >> 1, wn = wv & 1;
    const int r16 = lane & 15;
    const int kg = lane >> 4;

    auto stage = [&](int kt, int buf) {
        const int ko = kt * 64;
        {
            int c = tid;                         // 256 chunks = 32 rows x 8 kq
            int row = c >> 3, kq = c & 7, kqg = kq ^ (row & 7);
            gload_lds16(A1 + (size_t)(m0 + row) * 1024 + ko + kqg * 8, &lds[buf][c * 8]);
        }
#pragma unroll
        for (int is = 0; is < 4; ++is) {
            int c = is * 256 + tid;
            int row = c >> 3, kq = c & 7, kqg = kq ^ (row & 7);
            int wr = ((row >> 4) & 3) * 1024 + n0 + ((row >> 6) << 4) + (row & 15);
            gload_lds16(W1 + (size_t)wr * 1024 + ko + kqg * 8, &lds[buf][ATILE + c * 8]);
        }
    };

    floatx4 acc[4];
#pragma unroll
    for (int j = 0; j < 4; ++j) acc[j] = {0.f, 0.f, 0.f, 0.f};

    stage(0, 0);
    stage(1, 1);
    stage(2, 2);
    asm volatile("s_waitcnt vmcnt(%0)" :: "n"(2 * LOADS) : "memory");  // tile0 ready
    __builtin_amdgcn_s_barrier();
    CFENCE;

#pragma unroll 4
    for (int u = 0; u < 16; ++u) {
        const int cur = u & 3;
#pragma unroll
        for (int kk = 0; kk < 2; ++kk) {
            bf16x8 a, b[4];
            const int kqg = kk * 4 + kg;
            {
                int row = wm * 16 + r16;
                a = *(const bf16x8*)&lds[cur][row * 64 + (kqg ^ (row & 7)) * 8];
            }
#pragma unroll
            for (int j = 0; j < 4; ++j) {
                int row = wn * 64 + j * 16 + r16;
                b[j] = *(const bf16x8*)&lds[cur][ATILE + row * 64 + (kqg ^ (row & 7)) * 8];
            }
#pragma unroll
            for (int j = 0; j < 4; ++j)
                acc[j] = __builtin_amdgcn_mfma_f32_16x16x32_bf16(a, b[j], acc[j], 0, 0, 0);
        }
        if (u < 15) {
            __builtin_amdgcn_s_barrier();          // all waves done reading lds[cur]
            if (u < 13) {
                stage(u + 3, (u + 3) & 3);
                asm volatile("s_waitcnt vmcnt(%0)" :: "n"(2 * LOADS) : "memory");
            } else if (u == 13) {
                asm volatile("s_waitcnt vmcnt(%0)" :: "n"(LOADS) : "memory");
            } else {
                asm volatile("s_waitcnt vmcnt(0)" ::: "memory");
            }
            __builtin_amdgcn_s_barrier();
            CFENCE;
        }
    }

    const int h = n0 + wn * 16 + r16;
    unsigned short* hw = h_out;
    if ((m0 >> 8) == retire_t) hw = h_alt;

#pragma unroll
    for (int rg = 0; rg < 4; ++rg) {
        int m = m0 + wm * 16 + kg * 4 + rg;
        size_t mh = (size_t)m * 1024 + h;
        us4 pv = *(const us4*)(pre4b + mh * 4);
        float gi_ = acc[0][rg] + bf2f(pv.x);
        float gf_ = acc[1][rg] + bf2f(pv.y);
        float gg_ = acc[2][rg] + bf2f(pv.z);
        float go_ = acc[3][rg] + bf2f(pv.w);
        float co = c_in[mh];
        float iv = sigm(gi_), fv = sigm(gf_);
        float gv = tanh_fast(gg_), ov = sigm(go_);
        float cn = fv * co + iv * gv;
        float hn = ov * tanh_fast(cn);
        c_out[mh] = cn;
        hw[mh] = f2bf(hn);
    }
}

// ---------- launch ----------

extern "C" void kernel_launch(void* const* d_in, const int* in_sizes, int n_in,
                              void* d_out, int out_size, void* d_ws, size_t ws_size,
                              hipStream_t stream) {
    (void)in_sizes; (void)n_in; (void)out_size; (void)ws_size;
    const float* inputs   = (const float*)d_in[0];
    const float* roll_Wih = (const float*)d_in[1];
    const float* roll_Whh = (const float*)d_in[2];
    const float* roll_bih = (const float*)d_in[3];
    const float* roll_bhh = (const float*)d_in[4];
    const float* un_Wih   = (const float*)d_in[5];
    const float* un_Whh   = (const float*)d_in[6];
    const float* un_bih   = (const float*)d_in[7];
    const float* un_bhh   = (const float*)d_in[8];
    const float* cls_Wf   = (const float*)d_in[9];
    const float* cls_b    = (const float*)d_in[10];
    float* out = (float*)d_out;

    char* ws = (char*)d_ws;
    size_t off = 0;
    auto alloc = [&](size_t bytes) -> char* {
        char* p = ws + off;
        off += (bytes + 255) & ~(size_t)255;
        return p;
    };
    unsigned short* xt   = (unsigned short*)alloc(3584ull * 1024 * 2);
    unsigned short* rWih = (unsigned short*)alloc(4096ull * 1024 * 2);
    unsigned short* rWhh = (unsigned short*)alloc(4096ull * 1024 * 2);
    unsigned short* uWih = (unsigned short*)alloc(4096ull * 1024 * 2);
    unsigned short* uWhh = (unsigned short*)alloc(4096ull * 1024 * 2);
    unsigned short* cWp  = (unsigned short*)alloc(2560ull * 1024 * 2);
    float* rbias4 = (float*)alloc(1024 * 4 * 4);
    float* ubias4 = (float*)alloc(1024 * 4 * 4);
    unsigned short* XpreB  = (unsigned short*)alloc(3584ull * 4096 * 2);  // unroll x-proj bf16 [m][h][4]
    unsigned short* XrollB = (unsigned short*)alloc(3584ull * 4096 * 2);  // roll x-proj bf16 [m][h][4]
    float* uc     = (float*)alloc(3584ull * 1024 * 4);
    unsigned short* hb0    = (unsigned short*)alloc(3584ull * 1024 * 2);
    unsigned short* hb1    = (unsigned short*)alloc(3584ull * 1024 * 2);
    unsigned short* hfinal = (unsigned short*)alloc(3584ull * 1024 * 2);

    const size_t SF = 256 * 1024;

    // 1) conversions
    transpose_bt<<<3584, 256, 0, stream>>>(inputs, xt);
    conv_w4<<<16384, 256, 0, stream>>>(roll_Wih, roll_Whh, un_Wih, un_Whh,
                                       rWih, rWhh, uWih, uWhh);
    conv_cls<<<2560, 256, 0, stream>>>(cls_Wf, cWp);
    bias_interleave<<<16, 256, 0, stream>>>(roll_bih, roll_bhh, rbias4, 4096);
    bias_interleave<<<16, 256, 0, stream>>>(un_bih, un_bhh, ubias4, 4096);

    // 2) x-projections (hoisted; 64h tile, grid 28 x 16 = 448)
    lstm_big<3, 64><<<448, 256, 0, stream>>>(
        xt, uWih, nullptr, ubias4, nullptr, nullptr, nullptr, nullptr, -1,
        XpreB, nullptr, nullptr, 16);
    lstm_big<3, 64><<<448, 256, 0, stream>>>(
        xt, rWih, nullptr, rbias4, nullptr, nullptr, nullptr, nullptr, -1,
        XrollB, nullptr, nullptr, 16);

    // 3) rolling LSTM: t=0 elementwise, t>=1 ring-4 small GEMM
    cell_only<<<1024, 256, 0, stream>>>(XrollB, uc, hb0);
    for (int t = 1; t < 14; ++t) {
        lstm_small<<<256, 256, 0, stream>>>(
            hb0 + (size_t)(t - 1) * SF, rWhh,
            XrollB + (size_t)t * SF * 4,
            uc + (size_t)(t - 1) * SF, uc + (size_t)t * SF,
            hb0 + (size_t)t * SF, nullptr, -1, 32);
    }

    // 4) unrolling LSTM: shrinking prefix; retiring branch -> hfinal
    for (int s = 0; s <= 14; ++s) {
        int nb = (15 - s < 14) ? (15 - s) : 14;
        int M = nb * 256;
        const unsigned short* hsrc = (s & 1) ? hb1 : hb0;
        unsigned short* hdst = (s & 1) ? hb0 : hb1;
        int rt = (s >= 1) ? (14 - s) : -1;
        if (M >= 2304) {
            lstm_big<1, 64><<<M / 8, 256, 0, stream>>>(
                hsrc, uWhh, XpreB, nullptr, uc, uc, hdst, hfinal, rt,
                nullptr, nullptr, nullptr, 16);
        } else if (M >= 1024) {
            lstm_big<1, 32><<<M / 4, 256, 0, stream>>>(
                hsrc, uWhh, XpreB, nullptr, uc, uc, hdst, hfinal, rt,
                nullptr, nullptr, nullptr, 32);
        } else {
            lstm_small<<<M, 256, 0, stream>>>(
                hsrc, uWhh, XpreB, uc, uc, hdst, hfinal, rt, 32);
        }
    }

    // 5) classifier from hfinal (256-wide N, grid 28 x 10 = 280)
    lstm_big<2, 64><<<280, 256, 0, stream>>>(
        hfinal, cWp, nullptr, nullptr, nullptr, nullptr, nullptr, nullptr, -1,
        nullptr, cls_b, out, 10);
}